// Round 6
// baseline (471.403 us; speedup 1.0000x reference)
//
#include <hip/hip_runtime.h>
#include <stdint.h>

typedef __bf16 bf16x8 __attribute__((ext_vector_type(8)));
typedef float f32x4 __attribute__((ext_vector_type(4)));
typedef float f32x16 __attribute__((ext_vector_type(16)));
typedef unsigned short u16x8 __attribute__((ext_vector_type(8)));

__device__ __forceinline__ unsigned short f2bf(float f) {
  union { float f; uint32_t u; } v; v.f = f;
  uint32_t r = v.u + 0x7FFFu + ((v.u >> 16) & 1u);  // RNE
  return (unsigned short)(r >> 16);
}

__device__ __forceinline__ f32x4 mfma16(bf16x8 a, bf16x8 b, f32x4 c) {
  return __builtin_amdgcn_mfma_f32_16x16x32_bf16(a, b, c, 0, 0, 0);
}

__device__ __forceinline__ f32x16 mfma32(bf16x8 a, bf16x8 b, f32x16 c) {
  return __builtin_amdgcn_mfma_f32_32x32x16_bf16(a, b, c, 0, 0, 0);
}

// packed f32x2 -> bf16x2 (S0 -> low half). Verified in round 5.
__device__ __forceinline__ uint32_t cvtpk(float lo, float hi) {
  uint32_t r;
  asm("v_cvt_pk_bf16_f32 %0, %1, %2" : "=v"(r) : "v"(lo), "v"(hi));
  return r;
}

__device__ __forceinline__ void gload_lds16(const unsigned short* g, unsigned short* l) {
  __builtin_amdgcn_global_load_lds(
      (const __attribute__((address_space(1))) void*)g,
      (__attribute__((address_space(3))) void*)l, 16, 0, 0);
}

// 0.125 (hd^-0.5) * log2(e): folded into Q so softmax runs in exp2 domain.
#define SCALEQ 0.18033688011112042f
// fixed softmax shift (exp2 domain): logits ~N(0,1.44^2), max over 2.7e8 ~ 9 < 12.
#define FIXSHIFT 12.0f

// ---------------- x fp32 -> bf16 ----------------
__global__ __launch_bounds__(256) void convert_f32_bf16(const float* __restrict__ in,
                                                        unsigned short* __restrict__ outp) {
  int i = blockIdx.x * 256 + threadIdx.x;
  const float4* p = (const float4*)in + (size_t)i * 2;
  float4 a = p[0], b = p[1];
  u16x8 o;
  o[0] = f2bf(a.x); o[1] = f2bf(a.y); o[2] = f2bf(a.z); o[3] = f2bf(a.w);
  o[4] = f2bf(b.x); o[5] = f2bf(b.y); o[6] = f2bf(b.z); o[7] = f2bf(b.w);
  *(u16x8*)&outp[(size_t)i * 8] = o;
}

// ---------------- w [K][N] fp32 -> wT [N][K] bf16 ----------------
__global__ __launch_bounds__(256) void transpose_to_bf16(const float* __restrict__ w,
                                                         unsigned short* __restrict__ wT,
                                                         int K, int N) {
  __shared__ unsigned short tile[64][72];
  const int n0 = blockIdx.x * 64, k0 = blockIdx.y * 64;
  const int t = threadIdx.x;
  {
    const int r = t >> 4, c0 = (t & 15) * 4;
#pragma unroll
    for (int i = 0; i < 4; ++i) {
      int rr = r + i * 16;
      float4 v = *(const float4*)&w[(size_t)(k0 + rr) * N + n0 + c0];
      tile[c0 + 0][rr] = f2bf(v.x);
      tile[c0 + 1][rr] = f2bf(v.y);
      tile[c0 + 2][rr] = f2bf(v.z);
      tile[c0 + 3][rr] = f2bf(v.w);
    }
  }
  __syncthreads();
  {
    const int c = t >> 2, r0 = (t & 3) * 16;
    u16x8 o1, o2;
#pragma unroll
    for (int i = 0; i < 8; ++i) { o1[i] = tile[c][r0 + i]; o2[i] = tile[c][r0 + 8 + i]; }
    *(u16x8*)&wT[(size_t)(n0 + c) * K + k0 + r0] = o1;
    *(u16x8*)&wT[(size_t)(n0 + c) * K + k0 + r0 + 8] = o2;
  }
}

// ---------------- QKV GEMM: [8192,1024] x [1024,3072] + bias ----------------
__global__ __launch_bounds__(256) void qkv_gemm(const unsigned short* __restrict__ xbf,
                                                const unsigned short* __restrict__ wT,
                                                const float* __restrict__ bias,
                                                unsigned short* __restrict__ qb,
                                                unsigned short* __restrict__ kb,
                                                unsigned short* __restrict__ vtb) {
  __shared__ unsigned short As[128 * 32];
  __shared__ unsigned short Bs[128 * 32];
  const int tid = threadIdx.x, lane = tid & 63, wave = tid >> 6;
  const int mb = blockIdx.y * 128, nb = blockIdx.x * 128;
  const int wr = (wave >> 1) * 64, wc = (wave & 1) * 64;
  const int fr = lane & 15, fk = (lane >> 4) * 8;
  f32x4 acc[4][4] = {};
  for (int kt = 0; kt < 1024; kt += 32) {
    __syncthreads();
#pragma unroll
    for (int i = 0; i < 2; ++i) {
      int ch = wave * 128 + i * 64 + lane;
      int r = ch >> 2, ko = (ch & 3) * 8;
      gload_lds16(xbf + (size_t)(mb + r) * 1024 + kt + ko, &As[(wave * 128 + i * 64) * 8]);
      gload_lds16(wT + (size_t)(nb + r) * 1024 + kt + ko, &Bs[(wave * 128 + i * 64) * 8]);
    }
    __syncthreads();
    bf16x8 a[4], bq[4];
#pragma unroll
    for (int m = 0; m < 4; ++m) a[m] = *(const bf16x8*)&As[(wr + m * 16 + fr) * 32 + fk];
#pragma unroll
    for (int n = 0; n < 4; ++n) bq[n] = *(const bf16x8*)&Bs[(wc + n * 16 + fr) * 32 + fk];
#pragma unroll
    for (int m = 0; m < 4; ++m)
#pragma unroll
      for (int n = 0; n < 4; ++n) acc[m][n] = mfma16(a[m], bq[n], acc[m][n]);
  }
#pragma unroll
  for (int m = 0; m < 4; ++m)
#pragma unroll
    for (int n = 0; n < 4; ++n) {
      int col = nb + wc + n * 16 + fr;
      float bv = bias[col];
      int type = col >> 10, cc = col & 1023, h = cc >> 6, d = cc & 63;
#pragma unroll
      for (int j = 0; j < 4; ++j) {
        int row = mb + wr + m * 16 + (lane >> 4) * 4 + j;
        int bidx = row >> 11, s = row & 2047;
        float val = acc[m][n][j] + bv;
        if (type == 0)
          qb[(((size_t)(bidx * 16 + h)) * 2048 + s) * 64 + d] = f2bf(val * SCALEQ);
        else if (type == 1)
          kb[(((size_t)(bidx * 16 + h)) * 2048 + s) * 64 + d] = f2bf(val);
        else
          vtb[(((size_t)(bidx * 16 + h)) * 64 + d) * 2048 + s] = f2bf(val);
      }
    }
}

// ---------------- flash attention: 32x32 MFMA, straight-line k-loop ----------------
// vs round 5: (1) fixed-shift softmax (no max-track, no branch, shift folded into
// MFMA C-init), (2) k-permuted PV operands: P B-frag = cvtpk(sa) in place, V A-frag
// loads absorb the permutation (two b64 per 16-key chunk) -> ZERO cross-lane ops in
// the loop, (3) 32 q/wave, grid (16,64) = 4 waves/SIMD. l-reduce deferred to epilogue.
__global__ __launch_bounds__(256, 4) void attn_kernel(const unsigned short* __restrict__ qg,
                                                      const unsigned short* __restrict__ kgl,
                                                      const unsigned short* __restrict__ vtg,
                                                      unsigned short* __restrict__ attnb) {
  const int tid = threadIdx.x;
  const int lane = tid & 63, wave = tid >> 6;
  const int l31 = lane & 31, hl = lane >> 5;
  const int h8 = hl * 8, h4 = hl * 4;

  // XCD-locality remap: 8 bh per XCD (K+V of 8 bh = 4MB = one XCD L2)
  const int L = blockIdx.y * 16 + blockIdx.x;  // 0..1023
  const int xcd = L & 7, sl = L >> 3;
  const int bh = xcd * 8 + (sl & 7);
  const int qt = sl >> 3;  // 0..15
  const int b = bh >> 4, hh = bh & 15;

  const unsigned short* Qg = qg + (size_t)bh * 2048 * 64;
  const unsigned short* Kg = kgl + (size_t)bh * 2048 * 64;
  const unsigned short* Vg = vtg + (size_t)bh * 64 * 2048;
  const int q0 = qt * 128 + wave * 32;

  // persistent Q B-frags: col q = q0 + l31, d = dw*16 + h8 + {0..7}
  bf16x8 qf[4];
#pragma unroll
  for (int dw = 0; dw < 4; ++dw)
    qf[dw] = *(const bf16x8*)&Qg[(size_t)(q0 + l31) * 64 + dw * 16 + h8];

  f32x16 o0 = {}, o1 = {};
  f32x4 lacc = {0.f, 0.f, 0.f, 0.f};

  const unsigned short* vrow0 = Vg + (size_t)l31 * 2048;         // V^T row d = l31
  const unsigned short* vrow1 = Vg + (size_t)(32 + l31) * 2048;  // V^T row d = 32+l31

  union VU { uint32_t u[4]; bf16x8 v; };
  union PU { uint32_t u[4]; bf16x8 v; };

  for (int kbase = 0; kbase < 2048; kbase += 32) {
    // K A-frags: row key = kbase + l31, d = dw*16 + h8 + {0..7}
    const unsigned short* kr = &Kg[(size_t)(kbase + l31) * 64 + h8];
    bf16x8 k0 = *(const bf16x8*)&kr[0];
    bf16x8 k1 = *(const bf16x8*)&kr[16];
    bf16x8 k2 = *(const bf16x8*)&kr[32];
    bf16x8 k3 = *(const bf16x8*)&kr[48];

    // V^T A-frags with k-slot permutation pi = [0..3,8..11 | 4..7,12..15]:
    // k-slot hl*8+j  <->  key: chunk*16 + 4*hl + (j&3) + 8*(j>>2)
    VU va00, va01, va10, va11;
    *(uint2*)&va00.u[0] = *(const uint2*)&vrow0[kbase + h4];
    *(uint2*)&va00.u[2] = *(const uint2*)&vrow0[kbase + 8 + h4];
    *(uint2*)&va01.u[0] = *(const uint2*)&vrow0[kbase + 16 + h4];
    *(uint2*)&va01.u[2] = *(const uint2*)&vrow0[kbase + 24 + h4];
    *(uint2*)&va10.u[0] = *(const uint2*)&vrow1[kbase + h4];
    *(uint2*)&va10.u[2] = *(const uint2*)&vrow1[kbase + 8 + h4];
    *(uint2*)&va11.u[0] = *(const uint2*)&vrow1[kbase + 16 + h4];
    *(uint2*)&va11.u[2] = *(const uint2*)&vrow1[kbase + 24 + h4];

    // S^T - 12: init C to -FIXSHIFT (free bias), accumulate K x Q
    // sa[r] = S[key = kbase + (r&3) + 8*((r>>2)&1) + 16*(r>>3) + 4*hl][q0+l31] - 12
    f32x16 sa;
#pragma unroll
    for (int r = 0; r < 16; ++r) sa[r] = -FIXSHIFT;
    sa = mfma32(k0, qf[0], sa);
    sa = mfma32(k1, qf[1], sa);
    sa = mfma32(k2, qf[2], sa);
    sa = mfma32(k3, qf[3], sa);

    // fixed-shift softmax numerator: p = exp2(s - 12), no reduction needed now
#pragma unroll
    for (int r = 0; r < 16; ++r) sa[r] = __builtin_amdgcn_exp2f(sa[r]);
    // partial row-sum (per-lane half-row; cross-half deferred to epilogue)
#pragma unroll
    for (int j = 0; j < 4; ++j) lacc[j] += (sa[j] + sa[4 + j]) + (sa[8 + j] + sa[12 + j]);

    // P B-frags: in-place pack, zero lane-crossing (k-permutation matches V loads)
    // sa[0..7] = keys chunk0 {4hl+0..3, 8+4hl+0..3} = k-slots hl*8 + 0..7  (pi)
    PU p0, p1;
    p0.u[0] = cvtpk(sa[0], sa[1]);
    p0.u[1] = cvtpk(sa[2], sa[3]);
    p0.u[2] = cvtpk(sa[4], sa[5]);
    p0.u[3] = cvtpk(sa[6], sa[7]);
    p1.u[0] = cvtpk(sa[8], sa[9]);
    p1.u[1] = cvtpk(sa[10], sa[11]);
    p1.u[2] = cvtpk(sa[12], sa[13]);
    p1.u[3] = cvtpk(sa[14], sa[15]);

    // O^T += V^T x P^T
    o0 = mfma32(va00.v, p0.v, o0);
    o0 = mfma32(va01.v, p1.v, o0);
    o1 = mfma32(va10.v, p0.v, o1);
    o1 = mfma32(va11.v, p1.v, o1);
  }

  // epilogue: finish l (one cross-half shuffle), normalize, store
  float l = (lacc[0] + lacc[1]) + (lacc[2] + lacc[3]);
  l += __shfl_xor(l, 32);
  float invl = 1.0f / l;
  const size_t base = ((size_t)(b * 2048 + q0 + l31)) * 1024 + hh * 64;
#pragma unroll
  for (int r = 0; r < 16; ++r) {
    int d = (r & 3) + 8 * (r >> 2) + 4 * hl;
    attnb[base + d] = f2bf(o0[r] * invl);
    attnb[base + 32 + d] = f2bf(o1[r] * invl);
  }
}

// ---------------- proj GEMM: attn[8192,1024] x [1024,1024] + bias -> fp32 out ----------------
__global__ __launch_bounds__(256) void proj_gemm(const unsigned short* __restrict__ abf,
                                                 const unsigned short* __restrict__ wT,
                                                 const float* __restrict__ bias,
                                                 float* __restrict__ outp) {
  __shared__ unsigned short As[128 * 32];
  __shared__ unsigned short Bs[128 * 32];
  const int tid = threadIdx.x, lane = tid & 63, wave = tid >> 6;
  const int mb = blockIdx.y * 128, nb = blockIdx.x * 128;
  const int wr = (wave >> 1) * 64, wc = (wave & 1) * 64;
  const int fr = lane & 15, fk = (lane >> 4) * 8;
  f32x4 acc[4][4] = {};
  for (int kt = 0; kt < 1024; kt += 32) {
    __syncthreads();
#pragma unroll
    for (int i = 0; i < 2; ++i) {
      int ch = wave * 128 + i * 64 + lane;
      int r = ch >> 2, ko = (ch & 3) * 8;
      gload_lds16(abf + (size_t)(mb + r) * 1024 + kt + ko, &As[(wave * 128 + i * 64) * 8]);
      gload_lds16(wT + (size_t)(nb + r) * 1024 + kt + ko, &Bs[(wave * 128 + i * 64) * 8]);
    }
    __syncthreads();
    bf16x8 a[4], bq[4];
#pragma unroll
    for (int m = 0; m < 4; ++m) a[m] = *(const bf16x8*)&As[(wr + m * 16 + fr) * 32 + fk];
#pragma unroll
    for (int n = 0; n < 4; ++n) bq[n] = *(const bf16x8*)&Bs[(wc + n * 16 + fr) * 32 + fk];
#pragma unroll
    for (int m = 0; m < 4; ++m)
#pragma unroll
      for (int n = 0; n < 4; ++n) acc[m][n] = mfma16(a[m], bq[n], acc[m][n]);
  }
#pragma unroll
  for (int m = 0; m < 4; ++m)
#pragma unroll
    for (int n = 0; n < 4; ++n) {
      int col = nb + wc + n * 16 + fr;
      float bv = bias[col];
#pragma unroll
      for (int j = 0; j < 4; ++j) {
        int row = mb + wr + m * 16 + (lane >> 4) * 4 + j;
        outp[(size_t)row * 1024 + col] = acc[m][n][j] + bv;
      }
    }
}

extern "C" void kernel_launch(void* const* d_in, const int* in_sizes, int n_in,
                              void* d_out, int out_size, void* d_ws, size_t ws_size,
                              hipStream_t stream) {
  const float* x = (const float*)d_in[0];
  const float* w_qkv = (const float*)d_in[1];
  const float* b_qkv = (const float*)d_in[2];
  const float* w_proj = (const float*)d_in[3];
  const float* b_proj = (const float*)d_in[4];
  float* outp = (float*)d_out;
  char* ws = (char*)d_ws;

  const size_t OFF_XBF = 0;                 // 16,777,216 (also reused as attn output)
  const size_t OFF_WTQKV = 16777216;        //  6,291,456
  const size_t OFF_WTPROJ = 23068672;       //  2,097,152
  const size_t OFF_Q = 25165824;            // 16,777,216
  const size_t OFF_K = 41943040;            // 16,777,216
  const size_t OFF_VT = 58720256;           // 16,777,216
  const size_t NEED = 75497472;
  if (ws_size < NEED) return;

  unsigned short* xbf = (unsigned short*)(ws + OFF_XBF);
  unsigned short* wTqkv = (unsigned short*)(ws + OFF_WTQKV);
  unsigned short* wTproj = (unsigned short*)(ws + OFF_WTPROJ);
  unsigned short* qbuf = (unsigned short*)(ws + OFF_Q);
  unsigned short* kbuf = (unsigned short*)(ws + OFF_K);
  unsigned short* vtbuf = (unsigned short*)(ws + OFF_VT);
  unsigned short* attnb = xbf;  // alias: xbf dead after qkv_gemm

  hipLaunchKernelGGL(convert_f32_bf16, dim3(4096), dim3(256), 0, stream, x, xbf);
  hipLaunchKernelGGL(transpose_to_bf16, dim3(48, 16), dim3(256), 0, stream, w_qkv, wTqkv, 1024, 3072);
  hipLaunchKernelGGL(transpose_to_bf16, dim3(16, 16), dim3(256), 0, stream, w_proj, wTproj, 1024, 1024);
  hipLaunchKernelGGL(qkv_gemm, dim3(24, 64), dim3(256), 0, stream, xbf, wTqkv, b_qkv, qbuf, kbuf, vtbuf);
  hipLaunchKernelGGL(attn_kernel, dim3(16, 64), dim3(256), 0, stream, qbuf, kbuf, vtbuf, attnb);
  hipLaunchKernelGGL(proj_gemm, dim3(8, 64), dim3(256), 0, stream, attnb, wTproj, b_proj, outp);
}

// Round 8
// 230.341 us; speedup vs baseline: 2.0465x; 2.0465x over previous
//
#include <hip/hip_runtime.h>
#include <stdint.h>

typedef __bf16 bf16x8 __attribute__((ext_vector_type(8)));
typedef float f32x4 __attribute__((ext_vector_type(4)));
typedef float f32x16 __attribute__((ext_vector_type(16)));
typedef unsigned short u16x8 __attribute__((ext_vector_type(8)));

__device__ __forceinline__ unsigned short f2bf(float f) {
  union { float f; uint32_t u; } v; v.f = f;
  uint32_t r = v.u + 0x7FFFu + ((v.u >> 16) & 1u);  // RNE
  return (unsigned short)(r >> 16);
}

__device__ __forceinline__ f32x4 mfma16(bf16x8 a, bf16x8 b, f32x4 c) {
  return __builtin_amdgcn_mfma_f32_16x16x32_bf16(a, b, c, 0, 0, 0);
}

__device__ __forceinline__ f32x16 mfma32(bf16x8 a, bf16x8 b, f32x16 c) {
  return __builtin_amdgcn_mfma_f32_32x32x16_bf16(a, b, c, 0, 0, 0);
}

// packed f32x2 -> bf16x2 (S0 -> low half). Verified in rounds 5/6.
__device__ __forceinline__ uint32_t cvtpk(float lo, float hi) {
  uint32_t r;
  asm("v_cvt_pk_bf16_f32 %0, %1, %2" : "=v"(r) : "v"(lo), "v"(hi));
  return r;
}

__device__ __forceinline__ void gload_lds16(const unsigned short* g, unsigned short* l) {
  __builtin_amdgcn_global_load_lds(
      (const __attribute__((address_space(1))) void*)g,
      (__attribute__((address_space(3))) void*)l, 16, 0, 0);
}

// 0.125 (hd^-0.5) * log2(e): folded into Q so softmax runs in exp2 domain.
#define SCALEQ 0.18033688011112042f
// fixed softmax shift (exp2 domain): logits ~N(0,1.44^2), max over 2.7e8 ~ 9 < 12.
#define FIXSHIFT 12.0f

// ---------------- x fp32 -> bf16 ----------------
__global__ __launch_bounds__(256) void convert_f32_bf16(const float* __restrict__ in,
                                                        unsigned short* __restrict__ outp) {
  int i = blockIdx.x * 256 + threadIdx.x;
  const float4* p = (const float4*)in + (size_t)i * 2;
  float4 a = p[0], b = p[1];
  u16x8 o;
  o[0] = f2bf(a.x); o[1] = f2bf(a.y); o[2] = f2bf(a.z); o[3] = f2bf(a.w);
  o[4] = f2bf(b.x); o[5] = f2bf(b.y); o[6] = f2bf(b.z); o[7] = f2bf(b.w);
  *(u16x8*)&outp[(size_t)i * 8] = o;
}

// ---------------- w [K][N] fp32 -> wT [N][K] bf16 ----------------
__global__ __launch_bounds__(256) void transpose_to_bf16(const float* __restrict__ w,
                                                         unsigned short* __restrict__ wT,
                                                         int K, int N) {
  __shared__ unsigned short tile[64][72];
  const int n0 = blockIdx.x * 64, k0 = blockIdx.y * 64;
  const int t = threadIdx.x;
  {
    const int r = t >> 4, c0 = (t & 15) * 4;
#pragma unroll
    for (int i = 0; i < 4; ++i) {
      int rr = r + i * 16;
      float4 v = *(const float4*)&w[(size_t)(k0 + rr) * N + n0 + c0];
      tile[c0 + 0][rr] = f2bf(v.x);
      tile[c0 + 1][rr] = f2bf(v.y);
      tile[c0 + 2][rr] = f2bf(v.z);
      tile[c0 + 3][rr] = f2bf(v.w);
    }
  }
  __syncthreads();
  {
    const int c = t >> 2, r0 = (t & 3) * 16;
    u16x8 o1, o2;
#pragma unroll
    for (int i = 0; i < 8; ++i) { o1[i] = tile[c][r0 + i]; o2[i] = tile[c][r0 + 8 + i]; }
    *(u16x8*)&wT[(size_t)(n0 + c) * K + k0 + r0] = o1;
    *(u16x8*)&wT[(size_t)(n0 + c) * K + k0 + r0 + 8] = o2;
  }
}

// ---------------- QKV GEMM: [8192,1024] x [1024,3072] + bias ----------------
// Outputs: Q -> [bh][s][d] (scaled); K -> LINEAR [bh][s][d] (R6-proven);
// V -> FRAGMENT-LINEAR (under test this round):
//   Vf elem: ((bh*64 + s/32)*4 + (d/32)*2 + ((s>>4)&1))*512 + ((s>>2)&1)*256
//            + (d&31)*8 + (s&3) + 4*((s>>3)&1)
__global__ __launch_bounds__(256) void qkv_gemm(const unsigned short* __restrict__ xbf,
                                                const unsigned short* __restrict__ wT,
                                                const float* __restrict__ bias,
                                                unsigned short* __restrict__ qb,
                                                unsigned short* __restrict__ kb,
                                                unsigned short* __restrict__ vf) {
  __shared__ unsigned short As[128 * 32];
  __shared__ unsigned short Bs[128 * 32];
  const int tid = threadIdx.x, lane = tid & 63, wave = tid >> 6;
  const int mb = blockIdx.y * 128, nb = blockIdx.x * 128;
  const int wr = (wave >> 1) * 64, wc = (wave & 1) * 64;
  const int fr = lane & 15, fk = (lane >> 4) * 8;
  f32x4 acc[4][4] = {};
  for (int kt = 0; kt < 1024; kt += 32) {
    __syncthreads();
#pragma unroll
    for (int i = 0; i < 2; ++i) {
      int ch = wave * 128 + i * 64 + lane;
      int r = ch >> 2, ko = (ch & 3) * 8;
      gload_lds16(xbf + (size_t)(mb + r) * 1024 + kt + ko, &As[(wave * 128 + i * 64) * 8]);
      gload_lds16(wT + (size_t)(nb + r) * 1024 + kt + ko, &Bs[(wave * 128 + i * 64) * 8]);
    }
    __syncthreads();
    bf16x8 a[4], bq[4];
#pragma unroll
    for (int m = 0; m < 4; ++m) a[m] = *(const bf16x8*)&As[(wr + m * 16 + fr) * 32 + fk];
#pragma unroll
    for (int n = 0; n < 4; ++n) bq[n] = *(const bf16x8*)&Bs[(wc + n * 16 + fr) * 32 + fk];
#pragma unroll
    for (int m = 0; m < 4; ++m)
#pragma unroll
      for (int n = 0; n < 4; ++n) acc[m][n] = mfma16(a[m], bq[n], acc[m][n]);
  }
#pragma unroll
  for (int m = 0; m < 4; ++m)
#pragma unroll
    for (int n = 0; n < 4; ++n) {
      int col = nb + wc + n * 16 + fr;
      float bv = bias[col];
      int type = col >> 10, cc = col & 1023, h = cc >> 6, d = cc & 63;
#pragma unroll
      for (int j4 = 0; j4 < 4; ++j4) {
        int row = mb + wr + m * 16 + (lane >> 4) * 4 + j4;
        int bidx = row >> 11, s = row & 2047;
        int bh = bidx * 16 + h;
        float val = acc[m][n][j4] + bv;
        if (type == 0) {
          qb[(((size_t)bh) * 2048 + s) * 64 + d] = f2bf(val * SCALEQ);
        } else if (type == 1) {
          kb[(((size_t)bh) * 2048 + s) * 64 + d] = f2bf(val);
        } else {
          int t = s >> 5;
          int u = ((d >> 5) << 1) + ((s >> 4) & 1);
          int l = (((s >> 2) & 1) << 5) + (d & 31);
          int jj = (s & 3) + (((s >> 3) & 1) << 2);
          size_t idx = ((((size_t)bh * 64 + t) * 4 + u) * 64 + l) * 8 + jj;
          vf[idx] = f2bf(val);
        }
      }
    }
}

// ---------------- flash attention: 32x32 MFMA, straight-line k-loop ----------------
// Bisection round: all pieces from passing rounds (R5 geometry: 64 q/wave, 2 streams,
// grid (8,64); R6 compute: fixed-shift softmax + in-place cvtpk P-pack; R6 K linear
// row loads) EXCEPT the single suspect under test: fragment-linear Vf loads.
// No barrier, no manual double-buffer.
__global__ __launch_bounds__(256, 2) void attn_kernel(const unsigned short* __restrict__ qg,
                                                      const unsigned short* __restrict__ kgl,
                                                      const unsigned short* __restrict__ vf,
                                                      unsigned short* __restrict__ attnb) {
  const int tid = threadIdx.x;
  const int lane = tid & 63, wave = tid >> 6;
  const int l31 = lane & 31, hl = lane >> 5;
  const int h8 = hl * 8;

  // XCD-locality remap: 8 bh per XCD (K+Vf of 8 bh = 4MB = one XCD L2)
  const int L = blockIdx.y * 8 + blockIdx.x;  // 0..511
  const int xcd = L & 7, sl = L >> 3;
  const int bh = xcd * 8 + (sl & 7);
  const int qt = sl >> 3;  // 0..7
  const int b = bh >> 4, hh = bh & 15;

  const unsigned short* Qg = qg + (size_t)bh * 2048 * 64;
  const unsigned short* Kg = kgl + (size_t)bh * 2048 * 64;
  const unsigned short* VfB = vf + (size_t)bh * 131072 + lane * 8;
  const int q0 = qt * 256 + wave * 64;

  // persistent Q B-frags, 2 streams: col q = q0 + s2*32 + l31, d = dw*16 + h8 + {0..7}
  bf16x8 qf[2][4];
#pragma unroll
  for (int s2 = 0; s2 < 2; ++s2)
#pragma unroll
    for (int dw = 0; dw < 4; ++dw)
      qf[s2][dw] = *(const bf16x8*)&Qg[(size_t)(q0 + s2 * 32 + l31) * 64 + dw * 16 + h8];

  f32x16 o[2][2] = {};  // [stream][dblk]
  f32x4 lacc[2] = {};   // deferred row-sum partials

  union PU { uint32_t u[4]; bf16x8 v; };

  for (int kbase = 0; kbase < 2048; kbase += 32) {
    const int t = kbase >> 5;
    // K A-frags: LINEAR rows (R6-proven): row key = kbase + l31, d = dw*16 + h8
    const unsigned short* kr = &Kg[(size_t)(kbase + l31) * 64 + h8];
    bf16x8 k0 = *(const bf16x8*)&kr[0];
    bf16x8 k1 = *(const bf16x8*)&kr[16];
    bf16x8 k2 = *(const bf16x8*)&kr[32];
    bf16x8 k3 = *(const bf16x8*)&kr[48];
    // V A-frags: fragment-linear (SUSPECT UNDER TEST) — 4 coalesced 1KB loads
    // vA[i] elem e = V^T[d=(i>>1)*32+l31][key = t*32 + (i&1)*16 + 4*hl + (e&3) + 8*(e>>2)]
    bf16x8 vA0 = *(const bf16x8*)&VfB[(size_t)t * 2048 + 0 * 512];
    bf16x8 vA1 = *(const bf16x8*)&VfB[(size_t)t * 2048 + 1 * 512];
    bf16x8 vA2 = *(const bf16x8*)&VfB[(size_t)t * 2048 + 2 * 512];
    bf16x8 vA3 = *(const bf16x8*)&VfB[(size_t)t * 2048 + 3 * 512];

#pragma unroll
    for (int s2 = 0; s2 < 2; ++s2) {
      // S^T - 12: sa[r] = S[key = kbase + (r&3) + 8*((r>>2)&1) + 16*(r>>3) + 4*hl][q] - 12
      f32x16 sa;
#pragma unroll
      for (int r = 0; r < 16; ++r) sa[r] = -FIXSHIFT;
      sa = mfma32(k0, qf[s2][0], sa);
      sa = mfma32(k1, qf[s2][1], sa);
      sa = mfma32(k2, qf[s2][2], sa);
      sa = mfma32(k3, qf[s2][3], sa);

      // fixed-shift softmax numerator: p = exp2(s - 12)
#pragma unroll
      for (int r = 0; r < 16; ++r) sa[r] = __builtin_amdgcn_exp2f(sa[r]);
#pragma unroll
      for (int j = 0; j < 4; ++j)
        lacc[s2][j] += (sa[j] + sa[4 + j]) + (sa[8 + j] + sa[12 + j]);

      // P B-frags: in-place pack (R6-proven k-permutation, zero cross-lane)
      PU p0, p1;
      p0.u[0] = cvtpk(sa[0], sa[1]);   p0.u[1] = cvtpk(sa[2], sa[3]);
      p0.u[2] = cvtpk(sa[4], sa[5]);   p0.u[3] = cvtpk(sa[6], sa[7]);
      p1.u[0] = cvtpk(sa[8], sa[9]);   p1.u[1] = cvtpk(sa[10], sa[11]);
      p1.u[2] = cvtpk(sa[12], sa[13]); p1.u[3] = cvtpk(sa[14], sa[15]);

      // O^T += V^T x P^T
      o[s2][0] = mfma32(vA0, p0.v, o[s2][0]);
      o[s2][0] = mfma32(vA1, p1.v, o[s2][0]);
      o[s2][1] = mfma32(vA2, p0.v, o[s2][1]);
      o[s2][1] = mfma32(vA3, p1.v, o[s2][1]);
    }
  }

  // epilogue: finish l (one cross-half shuffle), normalize, store O^T
#pragma unroll
  for (int s2 = 0; s2 < 2; ++s2) {
    float l = (lacc[s2][0] + lacc[s2][1]) + (lacc[s2][2] + lacc[s2][3]);
    l += __shfl_xor(l, 32);
    float invl = 1.0f / l;
    const size_t base = ((size_t)(b * 2048 + q0 + s2 * 32 + l31)) * 1024 + hh * 64;
#pragma unroll
    for (int r = 0; r < 16; ++r) {
      int d = (r & 3) + 8 * (r >> 2) + 4 * hl;
      attnb[base + d] = f2bf(o[s2][0][r] * invl);
      attnb[base + 32 + d] = f2bf(o[s2][1][r] * invl);
    }
  }
}

// ---------------- proj GEMM: attn[8192,1024] x [1024,1024] + bias -> fp32 out ----------------
__global__ __launch_bounds__(256) void proj_gemm(const unsigned short* __restrict__ abf,
                                                 const unsigned short* __restrict__ wT,
                                                 const float* __restrict__ bias,
                                                 float* __restrict__ outp) {
  __shared__ unsigned short As[128 * 32];
  __shared__ unsigned short Bs[128 * 32];
  const int tid = threadIdx.x, lane = tid & 63, wave = tid >> 6;
  const int mb = blockIdx.y * 128, nb = blockIdx.x * 128;
  const int wr = (wave >> 1) * 64, wc = (wave & 1) * 64;
  const int fr = lane & 15, fk = (lane >> 4) * 8;
  f32x4 acc[4][4] = {};
  for (int kt = 0; kt < 1024; kt += 32) {
    __syncthreads();
#pragma unroll
    for (int i = 0; i < 2; ++i) {
      int ch = wave * 128 + i * 64 + lane;
      int r = ch >> 2, ko = (ch & 3) * 8;
      gload_lds16(abf + (size_t)(mb + r) * 1024 + kt + ko, &As[(wave * 128 + i * 64) * 8]);
      gload_lds16(wT + (size_t)(nb + r) * 1024 + kt + ko, &Bs[(wave * 128 + i * 64) * 8]);
    }
    __syncthreads();
    bf16x8 a[4], bq[4];
#pragma unroll
    for (int m = 0; m < 4; ++m) a[m] = *(const bf16x8*)&As[(wr + m * 16 + fr) * 32 + fk];
#pragma unroll
    for (int n = 0; n < 4; ++n) bq[n] = *(const bf16x8*)&Bs[(wc + n * 16 + fr) * 32 + fk];
#pragma unroll
    for (int m = 0; m < 4; ++m)
#pragma unroll
      for (int n = 0; n < 4; ++n) acc[m][n] = mfma16(a[m], bq[n], acc[m][n]);
  }
#pragma unroll
  for (int m = 0; m < 4; ++m)
#pragma unroll
    for (int n = 0; n < 4; ++n) {
      int col = nb + wc + n * 16 + fr;
      float bv = bias[col];
#pragma unroll
      for (int j = 0; j < 4; ++j) {
        int row = mb + wr + m * 16 + (lane >> 4) * 4 + j;
        outp[(size_t)row * 1024 + col] = acc[m][n][j] + bv;
      }
    }
}

extern "C" void kernel_launch(void* const* d_in, const int* in_sizes, int n_in,
                              void* d_out, int out_size, void* d_ws, size_t ws_size,
                              hipStream_t stream) {
  const float* x = (const float*)d_in[0];
  const float* w_qkv = (const float*)d_in[1];
  const float* b_qkv = (const float*)d_in[2];
  const float* w_proj = (const float*)d_in[3];
  const float* b_proj = (const float*)d_in[4];
  float* outp = (float*)d_out;
  char* ws = (char*)d_ws;

  const size_t OFF_XBF = 0;                 // 16,777,216 (also reused as attn output)
  const size_t OFF_WTQKV = 16777216;        //  6,291,456
  const size_t OFF_WTPROJ = 23068672;       //  2,097,152
  const size_t OFF_Q = 25165824;            // 16,777,216
  const size_t OFF_K = 41943040;            // 16,777,216 (linear K)
  const size_t OFF_VF = 58720256;           // 16,777,216 (fragment-linear V)
  const size_t NEED = 75497472;
  if (ws_size < NEED) return;

  unsigned short* xbf = (unsigned short*)(ws + OFF_XBF);
  unsigned short* wTqkv = (unsigned short*)(ws + OFF_WTQKV);
  unsigned short* wTproj = (unsigned short*)(ws + OFF_WTPROJ);
  unsigned short* qbuf = (unsigned short*)(ws + OFF_Q);
  unsigned short* kbuf = (unsigned short*)(ws + OFF_K);
  unsigned short* vfbuf = (unsigned short*)(ws + OFF_VF);
  unsigned short* attnb = xbf;  // alias: xbf dead after qkv_gemm

  hipLaunchKernelGGL(convert_f32_bf16, dim3(4096), dim3(256), 0, stream, x, xbf);
  hipLaunchKernelGGL(transpose_to_bf16, dim3(48, 16), dim3(256), 0, stream, w_qkv, wTqkv, 1024, 3072);
  hipLaunchKernelGGL(transpose_to_bf16, dim3(16, 16), dim3(256), 0, stream, w_proj, wTproj, 1024, 1024);
  hipLaunchKernelGGL(qkv_gemm, dim3(24, 64), dim3(256), 0, stream, xbf, wTqkv, b_qkv, qbuf, kbuf, vfbuf);
  hipLaunchKernelGGL(attn_kernel, dim3(8, 64), dim3(256), 0, stream, qbuf, kbuf, vfbuf, attnb);
  hipLaunchKernelGGL(proj_gemm, dim3(8, 64), dim3(256), 0, stream, attnb, wTproj, b_proj, outp);
}

// Round 10
// 209.491 us; speedup vs baseline: 2.2502x; 1.0995x over previous
//
#include <hip/hip_runtime.h>
#include <stdint.h>

typedef __bf16 bf16x8 __attribute__((ext_vector_type(8)));
typedef float f32x4 __attribute__((ext_vector_type(4)));
typedef float f32x16 __attribute__((ext_vector_type(16)));
typedef unsigned short u16x8 __attribute__((ext_vector_type(8)));

__device__ __forceinline__ unsigned short f2bf(float f) {
  union { float f; uint32_t u; } v; v.f = f;
  uint32_t r = v.u + 0x7FFFu + ((v.u >> 16) & 1u);  // RNE
  return (unsigned short)(r >> 16);
}

__device__ __forceinline__ f32x4 mfma16(bf16x8 a, bf16x8 b, f32x4 c) {
  return __builtin_amdgcn_mfma_f32_16x16x32_bf16(a, b, c, 0, 0, 0);
}

__device__ __forceinline__ f32x16 mfma32(bf16x8 a, bf16x8 b, f32x16 c) {
  return __builtin_amdgcn_mfma_f32_32x32x16_bf16(a, b, c, 0, 0, 0);
}

// packed f32x2 -> bf16x2 (S0 -> low half). Verified rounds 5/6/8.
__device__ __forceinline__ uint32_t cvtpk(float lo, float hi) {
  uint32_t r;
  asm("v_cvt_pk_bf16_f32 %0, %1, %2" : "=v"(r) : "v"(lo), "v"(hi));
  return r;
}

__device__ __forceinline__ void gload_lds16(const unsigned short* g, unsigned short* l) {
  __builtin_amdgcn_global_load_lds(
      (const __attribute__((address_space(1))) void*)g,
      (__attribute__((address_space(3))) void*)l, 16, 0, 0);
}

// 0.125 (hd^-0.5) * log2(e): folded into Q so softmax runs in exp2 domain.
#define SCALEQ 0.18033688011112042f
// fixed softmax shift (exp2 domain): logits ~N(0,1.44^2), max over 2.7e8 ~ 9 < 12.
#define FIXSHIFT 12.0f

// ---------------- x fp32 -> bf16 ----------------
__global__ __launch_bounds__(256) void convert_f32_bf16(const float* __restrict__ in,
                                                        unsigned short* __restrict__ outp) {
  int i = blockIdx.x * 256 + threadIdx.x;
  const float4* p = (const float4*)in + (size_t)i * 2;
  float4 a = p[0], b = p[1];
  u16x8 o;
  o[0] = f2bf(a.x); o[1] = f2bf(a.y); o[2] = f2bf(a.z); o[3] = f2bf(a.w);
  o[4] = f2bf(b.x); o[5] = f2bf(b.y); o[6] = f2bf(b.z); o[7] = f2bf(b.w);
  *(u16x8*)&outp[(size_t)i * 8] = o;
}

// ---------------- w [K][N] fp32 -> wT [N][K] bf16 ----------------
__global__ __launch_bounds__(256) void transpose_to_bf16(const float* __restrict__ w,
                                                         unsigned short* __restrict__ wT,
                                                         int K, int N) {
  __shared__ unsigned short tile[64][72];
  const int n0 = blockIdx.x * 64, k0 = blockIdx.y * 64;
  const int t = threadIdx.x;
  {
    const int r = t >> 4, c0 = (t & 15) * 4;
#pragma unroll
    for (int i = 0; i < 4; ++i) {
      int rr = r + i * 16;
      float4 v = *(const float4*)&w[(size_t)(k0 + rr) * N + n0 + c0];
      tile[c0 + 0][rr] = f2bf(v.x);
      tile[c0 + 1][rr] = f2bf(v.y);
      tile[c0 + 2][rr] = f2bf(v.z);
      tile[c0 + 3][rr] = f2bf(v.w);
    }
  }
  __syncthreads();
  {
    const int c = t >> 2, r0 = (t & 3) * 16;
    u16x8 o1, o2;
#pragma unroll
    for (int i = 0; i < 8; ++i) { o1[i] = tile[c][r0 + i]; o2[i] = tile[c][r0 + 8 + i]; }
    *(u16x8*)&wT[(size_t)(n0 + c) * K + k0 + r0] = o1;
    *(u16x8*)&wT[(size_t)(n0 + c) * K + k0 + r0 + 8] = o2;
  }
}

// ---------------- QKV GEMM: [8192,1024] x [1024,3072] + bias ----------------
// Outputs (R8-proven): Q -> [bh][s][d] (scaled); K -> LINEAR [bh][s][d];
// V -> FRAGMENT-LINEAR:
//   Vf elem: ((bh*64 + s/32)*4 + (d/32)*2 + ((s>>4)&1))*512 + ((s>>2)&1)*256
//            + (d&31)*8 + (s&3) + 4*((s>>3)&1)
__global__ __launch_bounds__(256) void qkv_gemm(const unsigned short* __restrict__ xbf,
                                                const unsigned short* __restrict__ wT,
                                                const float* __restrict__ bias,
                                                unsigned short* __restrict__ qb,
                                                unsigned short* __restrict__ kb,
                                                unsigned short* __restrict__ vf) {
  __shared__ unsigned short As[128 * 32];
  __shared__ unsigned short Bs[128 * 32];
  const int tid = threadIdx.x, lane = tid & 63, wave = tid >> 6;
  const int mb = blockIdx.y * 128, nb = blockIdx.x * 128;
  const int wr = (wave >> 1) * 64, wc = (wave & 1) * 64;
  const int fr = lane & 15, fk = (lane >> 4) * 8;
  f32x4 acc[4][4] = {};
  for (int kt = 0; kt < 1024; kt += 32) {
    __syncthreads();
#pragma unroll
    for (int i = 0; i < 2; ++i) {
      int ch = wave * 128 + i * 64 + lane;
      int r = ch >> 2, ko = (ch & 3) * 8;
      gload_lds16(xbf + (size_t)(mb + r) * 1024 + kt + ko, &As[(wave * 128 + i * 64) * 8]);
      gload_lds16(wT + (size_t)(nb + r) * 1024 + kt + ko, &Bs[(wave * 128 + i * 64) * 8]);
    }
    __syncthreads();
    bf16x8 a[4], bq[4];
#pragma unroll
    for (int m = 0; m < 4; ++m) a[m] = *(const bf16x8*)&As[(wr + m * 16 + fr) * 32 + fk];
#pragma unroll
    for (int n = 0; n < 4; ++n) bq[n] = *(const bf16x8*)&Bs[(wc + n * 16 + fr) * 32 + fk];
#pragma unroll
    for (int m = 0; m < 4; ++m)
#pragma unroll
      for (int n = 0; n < 4; ++n) acc[m][n] = mfma16(a[m], bq[n], acc[m][n]);
  }
#pragma unroll
  for (int m = 0; m < 4; ++m)
#pragma unroll
    for (int n = 0; n < 4; ++n) {
      int col = nb + wc + n * 16 + fr;
      float bv = bias[col];
      int type = col >> 10, cc = col & 1023, h = cc >> 6, d = cc & 63;
#pragma unroll
      for (int j4 = 0; j4 < 4; ++j4) {
        int row = mb + wr + m * 16 + (lane >> 4) * 4 + j4;
        int bidx = row >> 11, s = row & 2047;
        int bh = bidx * 16 + h;
        float val = acc[m][n][j4] + bv;
        if (type == 0) {
          qb[(((size_t)bh) * 2048 + s) * 64 + d] = f2bf(val * SCALEQ);
        } else if (type == 1) {
          kb[(((size_t)bh) * 2048 + s) * 64 + d] = f2bf(val);
        } else {
          int t = s >> 5;
          int u = ((d >> 5) << 1) + ((s >> 4) & 1);
          int l = (((s >> 2) & 1) << 5) + (d & 31);
          int jj = (s & 3) + (((s >> 3) & 1) << 2);
          size_t idx = ((((size_t)bh * 64 + t) * 4 + u) * 64 + l) * 8 + jj;
          vf[idx] = f2bf(val);
        }
      }
    }
}

// ---------------- flash attention: 32x32 MFMA, straight-line k-loop ----------------
// EXACTLY round 8 (passing: linear K rows, fragment-linear Vf, fixed-shift softmax,
// in-place cvtpk P-pack, 2 streams, grid (8,64)) PLUS ONLY:
//   (1) 2-deep register prefetch with NAMED scalar frags (bisection: prefetch alone)
//   (2) MFMA C-init from hoisted -12 constant vector
__global__ __launch_bounds__(256, 2) void attn_kernel(const unsigned short* __restrict__ qg,
                                                      const unsigned short* __restrict__ kgl,
                                                      const unsigned short* __restrict__ vf,
                                                      unsigned short* __restrict__ attnb) {
  const int tid = threadIdx.x;
  const int lane = tid & 63, wave = tid >> 6;
  const int l31 = lane & 31, hl = lane >> 5;
  const int h8 = hl * 8;

  // XCD-locality remap: 8 bh per XCD (K+Vf of 8 bh = 4MB = one XCD L2)
  const int L = blockIdx.y * 8 + blockIdx.x;  // 0..511
  const int xcd = L & 7, sl = L >> 3;
  const int bh = xcd * 8 + (sl & 7);
  const int qt = sl >> 3;  // 0..7
  const int b = bh >> 4, hh = bh & 15;

  const unsigned short* Qg = qg + (size_t)bh * 2048 * 64;
  const unsigned short* Kg = kgl + (size_t)bh * 2048 * 64;
  const unsigned short* VfB = vf + (size_t)bh * 131072 + lane * 8;
  const int q0 = qt * 256 + wave * 64;

  // persistent Q B-frags, 2 streams: col q = q0 + s2*32 + l31, d = dw*16 + h8 + {0..7}
  bf16x8 qf[2][4];
#pragma unroll
  for (int s2 = 0; s2 < 2; ++s2)
#pragma unroll
    for (int dw = 0; dw < 4; ++dw)
      qf[s2][dw] = *(const bf16x8*)&Qg[(size_t)(q0 + s2 * 32 + l31) * 64 + dw * 16 + h8];

  f32x16 o[2][2] = {};  // [stream][dblk]
  f32x4 lacc[2] = {};   // deferred row-sum partials

  f32x16 cinit;
#pragma unroll
  for (int r = 0; r < 16; ++r) cinit[r] = -FIXSHIFT;

  union PU { uint32_t u[4]; bf16x8 v; };

  // double-buffered fragment registers: NAMED scalars
  bf16x8 ka0, ka1, ka2, ka3, va0, va1, va2, va3;
  bf16x8 kb0, kb1, kb2, kb3, vb0, vb1, vb2, vb3;
  {
    const unsigned short* kr = &Kg[(size_t)l31 * 64 + h8];
    ka0 = *(const bf16x8*)&kr[0];
    ka1 = *(const bf16x8*)&kr[16];
    ka2 = *(const bf16x8*)&kr[32];
    ka3 = *(const bf16x8*)&kr[48];
    va0 = *(const bf16x8*)&VfB[0];
    va1 = *(const bf16x8*)&VfB[512];
    va2 = *(const bf16x8*)&VfB[1024];
    va3 = *(const bf16x8*)&VfB[1536];
  }

  // One 32-key x 64-q tile step (R8 numerics, C-init hoisted).
#define STEP(K0, K1, K2, K3, V0, V1, V2, V3)                                  \
  {                                                                           \
    _Pragma("unroll")                                                         \
    for (int s2 = 0; s2 < 2; ++s2) {                                          \
      f32x16 sa = mfma32(K0, qf[s2][0], cinit);                               \
      sa = mfma32(K1, qf[s2][1], sa);                                         \
      sa = mfma32(K2, qf[s2][2], sa);                                         \
      sa = mfma32(K3, qf[s2][3], sa);                                         \
      _Pragma("unroll")                                                       \
      for (int r = 0; r < 16; ++r) sa[r] = __builtin_amdgcn_exp2f(sa[r]);     \
      _Pragma("unroll")                                                       \
      for (int j = 0; j < 4; ++j)                                             \
        lacc[s2][j] += (sa[j] + sa[4 + j]) + (sa[8 + j] + sa[12 + j]);        \
      PU p0, p1;                                                              \
      p0.u[0] = cvtpk(sa[0], sa[1]);   p0.u[1] = cvtpk(sa[2], sa[3]);         \
      p0.u[2] = cvtpk(sa[4], sa[5]);   p0.u[3] = cvtpk(sa[6], sa[7]);         \
      p1.u[0] = cvtpk(sa[8], sa[9]);   p1.u[1] = cvtpk(sa[10], sa[11]);       \
      p1.u[2] = cvtpk(sa[12], sa[13]); p1.u[3] = cvtpk(sa[14], sa[15]);       \
      o[s2][0] = mfma32(V0, p0.v, o[s2][0]);                                  \
      o[s2][0] = mfma32(V1, p1.v, o[s2][0]);                                  \
      o[s2][1] = mfma32(V2, p0.v, o[s2][1]);                                  \
      o[s2][1] = mfma32(V3, p1.v, o[s2][1]);                                  \
    }                                                                         \
  }

  for (int t = 0; t < 64; t += 2) {
    // prefetch tile t+1 into b-set
    {
      const unsigned short* kr = &Kg[(size_t)((t + 1) * 32 + l31) * 64 + h8];
      const unsigned short* vp = VfB + (size_t)(t + 1) * 2048;
      kb0 = *(const bf16x8*)&kr[0];
      kb1 = *(const bf16x8*)&kr[16];
      kb2 = *(const bf16x8*)&kr[32];
      kb3 = *(const bf16x8*)&kr[48];
      vb0 = *(const bf16x8*)&vp[0];
      vb1 = *(const bf16x8*)&vp[512];
      vb2 = *(const bf16x8*)&vp[1024];
      vb3 = *(const bf16x8*)&vp[1536];
    }
    STEP(ka0, ka1, ka2, ka3, va0, va1, va2, va3);
    if (t + 2 < 64) {
      const unsigned short* kr = &Kg[(size_t)((t + 2) * 32 + l31) * 64 + h8];
      const unsigned short* vp = VfB + (size_t)(t + 2) * 2048;
      ka0 = *(const bf16x8*)&kr[0];
      ka1 = *(const bf16x8*)&kr[16];
      ka2 = *(const bf16x8*)&kr[32];
      ka3 = *(const bf16x8*)&kr[48];
      va0 = *(const bf16x8*)&vp[0];
      va1 = *(const bf16x8*)&vp[512];
      va2 = *(const bf16x8*)&vp[1024];
      va3 = *(const bf16x8*)&vp[1536];
    }
    STEP(kb0, kb1, kb2, kb3, vb0, vb1, vb2, vb3);
  }
#undef STEP

  // epilogue: finish l (one cross-half shuffle), normalize, store O^T
#pragma unroll
  for (int s2 = 0; s2 < 2; ++s2) {
    float l = (lacc[s2][0] + lacc[s2][1]) + (lacc[s2][2] + lacc[s2][3]);
    l += __shfl_xor(l, 32);
    float invl = 1.0f / l;
    const size_t base = ((size_t)(b * 2048 + q0 + s2 * 32 + l31)) * 1024 + hh * 64;
#pragma unroll
    for (int r = 0; r < 16; ++r) {
      int d = (r & 3) + 8 * (r >> 2) + 4 * hl;
      attnb[base + d] = f2bf(o[s2][0][r] * invl);
      attnb[base + 32 + d] = f2bf(o[s2][1][r] * invl);
    }
  }
}

// ---------------- proj GEMM: attn[8192,1024] x [1024,1024] + bias -> fp32 out ----------------
__global__ __launch_bounds__(256) void proj_gemm(const unsigned short* __restrict__ abf,
                                                 const unsigned short* __restrict__ wT,
                                                 const float* __restrict__ bias,
                                                 float* __restrict__ outp) {
  __shared__ unsigned short As[128 * 32];
  __shared__ unsigned short Bs[128 * 32];
  const int tid = threadIdx.x, lane = tid & 63, wave = tid >> 6;
  const int mb = blockIdx.y * 128, nb = blockIdx.x * 128;
  const int wr = (wave >> 1) * 64, wc = (wave & 1) * 64;
  const int fr = lane & 15, fk = (lane >> 4) * 8;
  f32x4 acc[4][4] = {};
  for (int kt = 0; kt < 1024; kt += 32) {
    __syncthreads();
#pragma unroll
    for (int i = 0; i < 2; ++i) {
      int ch = wave * 128 + i * 64 + lane;
      int r = ch >> 2, ko = (ch & 3) * 8;
      gload_lds16(abf + (size_t)(mb + r) * 1024 + kt + ko, &As[(wave * 128 + i * 64) * 8]);
      gload_lds16(wT + (size_t)(nb + r) * 1024 + kt + ko, &Bs[(wave * 128 + i * 64) * 8]);
    }
    __syncthreads();
    bf16x8 a[4], bq[4];
#pragma unroll
    for (int m = 0; m < 4; ++m) a[m] = *(const bf16x8*)&As[(wr + m * 16 + fr) * 32 + fk];
#pragma unroll
    for (int n = 0; n < 4; ++n) bq[n] = *(const bf16x8*)&Bs[(wc + n * 16 + fr) * 32 + fk];
#pragma unroll
    for (int m = 0; m < 4; ++m)
#pragma unroll
      for (int n = 0; n < 4; ++n) acc[m][n] = mfma16(a[m], bq[n], acc[m][n]);
  }
#pragma unroll
  for (int m = 0; m < 4; ++m)
#pragma unroll
    for (int n = 0; n < 4; ++n) {
      int col = nb + wc + n * 16 + fr;
      float bv = bias[col];
#pragma unroll
      for (int j = 0; j < 4; ++j) {
        int row = mb + wr + m * 16 + (lane >> 4) * 4 + j;
        outp[(size_t)row * 1024 + col] = acc[m][n][j] + bv;
      }
    }
}

extern "C" void kernel_launch(void* const* d_in, const int* in_sizes, int n_in,
                              void* d_out, int out_size, void* d_ws, size_t ws_size,
                              hipStream_t stream) {
  const float* x = (const float*)d_in[0];
  const float* w_qkv = (const float*)d_in[1];
  const float* b_qkv = (const float*)d_in[2];
  const float* w_proj = (const float*)d_in[3];
  const float* b_proj = (const float*)d_in[4];
  float* outp = (float*)d_out;
  char* ws = (char*)d_ws;

  const size_t OFF_XBF = 0;                 // 16,777,216 (also reused as attn output)
  const size_t OFF_WTQKV = 16777216;        //  6,291,456
  const size_t OFF_WTPROJ = 23068672;       //  2,097,152
  const size_t OFF_Q = 25165824;            // 16,777,216
  const size_t OFF_K = 41943040;            // 16,777,216 (linear K)
  const size_t OFF_VF = 58720256;           // 16,777,216 (fragment-linear V)
  const size_t NEED = 75497472;
  if (ws_size < NEED) return;

  unsigned short* xbf = (unsigned short*)(ws + OFF_XBF);
  unsigned short* wTqkv = (unsigned short*)(ws + OFF_WTQKV);
  unsigned short* wTproj = (unsigned short*)(ws + OFF_WTPROJ);
  unsigned short* qbuf = (unsigned short*)(ws + OFF_Q);
  unsigned short* kbuf = (unsigned short*)(ws + OFF_K);
  unsigned short* vfbuf = (unsigned short*)(ws + OFF_VF);
  unsigned short* attnb = xbf;  // alias: xbf dead after qkv_gemm

  hipLaunchKernelGGL(convert_f32_bf16, dim3(4096), dim3(256), 0, stream, x, xbf);
  hipLaunchKernelGGL(transpose_to_bf16, dim3(48, 16), dim3(256), 0, stream, w_qkv, wTqkv, 1024, 3072);
  hipLaunchKernelGGL(transpose_to_bf16, dim3(16, 16), dim3(256), 0, stream, w_proj, wTproj, 1024, 1024);
  hipLaunchKernelGGL(qkv_gemm, dim3(24, 64), dim3(256), 0, stream, xbf, wTqkv, b_qkv, qbuf, kbuf, vfbuf);
  hipLaunchKernelGGL(attn_kernel, dim3(8, 64), dim3(256), 0, stream, qbuf, kbuf, vfbuf, attnb);
  hipLaunchKernelGGL(proj_gemm, dim3(8, 64), dim3(256), 0, stream, attnb, wTproj, b_proj, outp);
}